// Round 9
// baseline (60.280 us; speedup 1.0000x reference)
//
#include <hip/hip_runtime.h>
#include <math.h>

#define NUM_CLASSES 200
#define NUM_PROTO   10
#define EMBED_D     512
#define NTOK        8192
#define INV_EPS     100.0f
#define EPSF        0.01f
#define MOM         0.02f
#define ITERS       5
#define CAPJ        128     // max class size (binomial mu=41 sigma=6.4; +13.6 sigma)

__device__ __forceinline__ float wave_sum(float v) {
#pragma unroll
    for (int o = 32; o; o >>= 1) v += __shfl_xor(v, o);
    return v;
}
__device__ __forceinline__ float wave_max(float v) {
#pragma unroll
    for (int o = 32; o; o >>= 1) v = fmaxf(v, __shfl_xor(v, o));
    return v;
}

// ---- single fused kernel: one block per class does EVERYTHING -------------
// phase 0: class-local count + stable rank of own tokens (scan, no atomics)
// phase 1: similarities S[10][cnt] -> LDS (wave-pairs: 5 protos each,
//          4-deep batched token loads)
// phase 2: Sinkhorn, BARRIER-FREE: every wave redundantly runs all 5 iters
//          in registers (2 column segments per lane); final v-update dropped
//          (cancels in pi/pi.sum(0)); weights stay in registers
// phase 3: accumulate new_proto (16 waves = 4 dimgroups x 4 j-slices),
//          4-deep batched loads, weights via wave-local shfl broadcast
// phase 4: reduce j-slices + momentum blend; phase 5: L2 normalize + write
__global__ __launch_bounds__(1024) void k_all(
        const float* __restrict__ tokens,
        const int*   __restrict__ labels,
        const float* __restrict__ protos,
        float*       __restrict__ out) {
    __shared__ float S_sh[NUM_PROTO][CAPJ];    // 5 KB
    __shared__ float red[16][NUM_PROTO][128];  // 80 KB
    __shared__ float o_sh[NUM_PROTO][EMBED_D]; // 20 KB
    __shared__ float inv_l[CAPJ];
    __shared__ int   idx_l[CAPJ];
    __shared__ int   weq[16];

    const int c    = blockIdx.x;
    const int tid  = threadIdx.x;
    const int lane = tid & 63;
    const int wave = tid >> 6;

    // ---- phase 0: each thread owns 8 consecutive labels; scan ranks -------
    int4 la = *(const int4*)(labels + tid * 8);
    int4 lb = *(const int4*)(labels + tid * 8 + 4);
    int l[8] = {la.x, la.y, la.z, la.w, lb.x, lb.y, lb.z, lb.w};
    int meq = 0;
#pragma unroll
    for (int i = 0; i < 8; ++i) meq += (l[i] == c);
    int incl = meq;
#pragma unroll
    for (int o = 1; o < 64; o <<= 1) { int t = __shfl_up(incl, o); if (lane >= o) incl += t; }
    if (lane == 63) weq[wave] = incl;
    __syncthreads();
    int cnt = 0, wbase = 0;
#pragma unroll
    for (int w = 0; w < 16; ++w) { int q = weq[w]; cnt += q; if (w < wave) wbase += q; }
    if (cnt > CAPJ) cnt = CAPJ;                // unreachable memory-safety clamp
    int pos = wbase + incl - meq;
#pragma unroll
    for (int i = 0; i < 8; ++i)
        if (l[i] == c && pos < CAPJ) { idx_l[pos] = tid * 8 + i; ++pos; }
    __syncthreads();

    // ---- phase 1: similarities; wave-pair wp: token j, 5 protos; 4-deep ---
    {
        const int wp = wave >> 1, ph = wave & 1;
        float preg[5][8];
        const float* pb = protos + (size_t)(c * NUM_PROTO + ph * 5) * EMBED_D + lane * 8;
#pragma unroll
        for (int p = 0; p < 5; ++p) {
            float4 x = *(const float4*)(pb + p * EMBED_D);
            float4 y = *(const float4*)(pb + p * EMBED_D + 4);
            preg[p][0]=x.x; preg[p][1]=x.y; preg[p][2]=x.z; preg[p][3]=x.w;
            preg[p][4]=y.x; preg[p][5]=y.y; preg[p][6]=y.z; preg[p][7]=y.w;
        }
        for (int j0 = wp; j0 < cnt; j0 += 32) {      // 4 tokens in flight
            float4 A[4], B[4];
#pragma unroll
            for (int k = 0; k < 4; ++k) {
                int j = j0 + 8 * k;
                if (j < cnt) {
                    const float* tr = tokens + (size_t)idx_l[j] * EMBED_D + lane * 8;
                    A[k] = *(const float4*)tr;
                    B[k] = *(const float4*)(tr + 4);
                }
            }
#pragma unroll
            for (int k = 0; k < 4; ++k) {
                int j = j0 + 8 * k;
                if (j < cnt) {
                    float4 ta = A[k], tb = B[k];
                    float ssq = ta.x*ta.x + ta.y*ta.y + ta.z*ta.z + ta.w*ta.w
                              + tb.x*tb.x + tb.y*tb.y + tb.z*tb.z + tb.w*tb.w;
                    ssq = wave_sum(ssq);
                    float inv = 1.0f / sqrtf(ssq);
                    if (ph == 0 && lane == 0) inv_l[j] = inv;
#pragma unroll
                    for (int p = 0; p < 5; ++p) {
                        float d = preg[p][0]*ta.x + preg[p][1]*ta.y + preg[p][2]*ta.z + preg[p][3]*ta.w
                                + preg[p][4]*tb.x + preg[p][5]*tb.y + preg[p][6]*tb.z + preg[p][7]*tb.w;
                        d = wave_sum(d);
                        if (lane == 0) S_sh[ph * 5 + p][j] = d * inv;
                    }
                }
            }
        }
    }
    __syncthreads();

    // ---- phase 2: barrier-free Sinkhorn, redundant per wave ---------------
    const float log_a = -2.3025850f;           // log(0.1 + 1e-8)
    const float log_b = __logf(1.0f / (float)(cnt > 0 ? cnt : 1) + 1e-8f);
    const bool ok_a = lane < cnt, ok_b = lane + 64 < cnt;
    float Sa[NUM_PROTO], Sb[NUM_PROTO], u[NUM_PROTO];
#pragma unroll
    for (int p = 0; p < NUM_PROTO; ++p) {
        Sa[p] = ok_a ? S_sh[p][lane]      : -1e30f;
        Sb[p] = ok_b ? S_sh[p][lane + 64] : -1e30f;
    }
    float va = 0.0f, vb = 0.0f;
    for (int it = 0; it < ITERS; ++it) {
#pragma unroll
        for (int p = 0; p < NUM_PROTO; ++p) {
            float xa = (Sa[p] + va) * INV_EPS;
            float xb = (Sb[p] + vb) * INV_EPS;
            float M  = wave_max(fmaxf(xa, xb));
            float sm = wave_sum(__expf(xa - M) + __expf(xb - M));
            u[p] = EPSF * (log_a - (M + __logf(sm)));
        }
        if (it < ITERS - 1) {                  // final v-update cancels in pi/colsum
            if (ok_a) {
                float x[NUM_PROTO], m = -1e30f;
#pragma unroll
                for (int p = 0; p < NUM_PROTO; ++p) { x[p] = (Sa[p] + u[p]) * INV_EPS; m = fmaxf(m, x[p]); }
                float sm = 0.0f;
#pragma unroll
                for (int p = 0; p < NUM_PROTO; ++p) sm += __expf(x[p] - m);
                va = EPSF * (log_b - (m + __logf(sm)));
            }
            if (ok_b) {
                float x[NUM_PROTO], m = -1e30f;
#pragma unroll
                for (int p = 0; p < NUM_PROTO; ++p) { x[p] = (Sb[p] + u[p]) * INV_EPS; m = fmaxf(m, x[p]); }
                float sm = 0.0f;
#pragma unroll
                for (int p = 0; p < NUM_PROTO; ++p) sm += __expf(x[p] - m);
                vb = EPSF * (log_b - (m + __logf(sm)));
            }
        }
    }
    // weights in registers: w[p][col] = softmax_p((S+u)/eps) * inv_norm
    float wa[NUM_PROTO], wb[NUM_PROTO];
    {
        float xa[NUM_PROTO], xb[NUM_PROTO], ma = -1e30f, mb = -1e30f;
#pragma unroll
        for (int p = 0; p < NUM_PROTO; ++p) {
            xa[p] = (Sa[p] + u[p]) * INV_EPS; ma = fmaxf(ma, xa[p]);
            xb[p] = (Sb[p] + u[p]) * INV_EPS; mb = fmaxf(mb, xb[p]);
        }
        float ca = 0.0f, cb = 0.0f;
#pragma unroll
        for (int p = 0; p < NUM_PROTO; ++p) {
            wa[p] = __expf(xa[p] - ma); ca += wa[p];
            wb[p] = __expf(xb[p] - mb); cb += wb[p];
        }
        float sa = ok_a ? inv_l[lane]      / ca : 0.0f;
        float sb = ok_b ? inv_l[lane + 64] / cb : 0.0f;
#pragma unroll
        for (int p = 0; p < NUM_PROTO; ++p) { wa[p] *= sa; wb[p] *= sb; }
    }

    // ---- phase 3: accumulate; wave (g,js): dims [g*128,+128), 4-deep ------
    const int g  = wave >> 2, js = wave & 3;
    const int d0 = g * 128 + lane * 2;
    float acc[NUM_PROTO][2];
#pragma unroll
    for (int p = 0; p < NUM_PROTO; ++p) { acc[p][0] = 0.0f; acc[p][1] = 0.0f; }
    for (int j0 = js; j0 < cnt; j0 += 16) {          // 4 tokens in flight
        float2 T[4];
#pragma unroll
        for (int k = 0; k < 4; ++k) {
            int j = j0 + 4 * k;
            if (j < cnt) T[k] = *(const float2*)(tokens + (size_t)idx_l[j] * EMBED_D + d0);
        }
#pragma unroll
        for (int k = 0; k < 4; ++k) {
            int j = j0 + 4 * k;
            if (j < cnt) {
#pragma unroll
                for (int p = 0; p < NUM_PROTO; ++p) {
                    float w = __shfl((j < 64) ? wa[p] : wb[p], j & 63);
                    acc[p][0] += w * T[k].x;
                    acc[p][1] += w * T[k].y;
                }
            }
        }
    }
#pragma unroll
    for (int p = 0; p < NUM_PROTO; ++p)
        *(float2*)&red[wave][p][lane * 2] = make_float2(acc[p][0], acc[p][1]);
    __syncthreads();

    // ---- phase 4: reduce j-slices + momentum blend ------------------------
    for (int e4 = tid; e4 < NUM_PROTO * EMBED_D; e4 += 1024) {
        int p  = e4 >> 9;
        int d  = e4 & 511;
        int gg = d >> 7;
        int dd = d & 127;
        float s = red[gg * 4 + 0][p][dd] + red[gg * 4 + 1][p][dd]
                + red[gg * 4 + 2][p][dd] + red[gg * 4 + 3][p][dd];
        int row = c * NUM_PROTO + p;
        o_sh[p][d] = (1.0f - MOM) * protos[(size_t)row * EMBED_D + d] + MOM * s;
    }
    __syncthreads();

    // ---- phase 5: per-row L2 normalize + write ----------------------------
    if (wave < NUM_PROTO) {
        const float* orow = &o_sh[wave][0];
        float4 a = *(const float4*)(orow + lane * 8);
        float4 b = *(const float4*)(orow + lane * 8 + 4);
        float ss = a.x*a.x + a.y*a.y + a.z*a.z + a.w*a.w
                 + b.x*b.x + b.y*b.y + b.z*b.z + b.w*b.w;
        ss = wave_sum(ss);
        float inv = 1.0f / sqrtf(ss);
        int row = c * NUM_PROTO + wave;
        float* od = out + (size_t)row * EMBED_D + lane * 8;
        float4 w0 = make_float4(a.x*inv, a.y*inv, a.z*inv, a.w*inv);
        float4 w1 = make_float4(b.x*inv, b.y*inv, b.z*inv, b.w*inv);
        *(float4*)od       = w0;
        *(float4*)(od + 4) = w1;
    }
}

extern "C" void kernel_launch(void* const* d_in, const int* in_sizes, int n_in,
                              void* d_out, int out_size, void* d_ws, size_t ws_size,
                              hipStream_t stream) {
    const float* tokens = (const float*)d_in[0];
    const int*   labels = (const int*)d_in[1];
    const float* protos = (const float*)d_in[2];
    float* out = (float*)d_out;
    (void)d_ws; (void)ws_size; (void)in_sizes; (void)n_in; (void)out_size;

    k_all<<<NUM_CLASSES, 1024, 0, stream>>>(tokens, labels, protos, out);
}

// Round 10
// 42.348 us; speedup vs baseline: 1.4235x; 1.4235x over previous
//
#include <hip/hip_runtime.h>
#include <math.h>

#define NUM_CLASSES 200
#define NUM_PROTO   10
#define EMBED_D     512
#define NTOK        8192
#define INV_EPS     100.0f
#define EPSF        0.01f
#define MOM         0.02f
#define ITERS       5
#define CAPJ        128     // max class size (binomial mu=41 sigma=6.4; +13.6 sigma)

__device__ __forceinline__ float wave_sum(float v) {
#pragma unroll
    for (int o = 32; o; o >>= 1) v += __shfl_xor(v, o);
    return v;
}
__device__ __forceinline__ float wave_max(float v) {
#pragma unroll
    for (int o = 32; o; o >>= 1) v = fmaxf(v, __shfl_xor(v, o));
    return v;
}

// ---- single fused kernel: one block per class does EVERYTHING -------------
// phase 0: class-local count + stable rank of own tokens (scan, no atomics)
// phase 1: similarities S[10][cnt] into LDS (wave-pairs: 5 protos each,
//          1-deep token-row prefetch)
// phase 2: Sinkhorn on WAVE 0 ONLY, fully in registers (2 column segments),
//          zero barriers inside iterations; final v-update dropped (cancels
//          in pi/pi.sum(0)); weights written to LDS once, ONE barrier
// phase 3: accumulate new_proto (16 waves = 4 dimgroups x 4 j-slices)
// phase 4: reduce + momentum blend; phase 5: L2 normalize + write
__global__ __launch_bounds__(1024) void k_all(
        const float* __restrict__ tokens,
        const int*   __restrict__ labels,
        const float* __restrict__ protos,
        float*       __restrict__ out) {
    __shared__ float S_sh[NUM_PROTO][CAPJ];    // 5 KB (sims -> weights)
    __shared__ float red[16][NUM_PROTO][128];  // 80 KB
    __shared__ float o_sh[NUM_PROTO][EMBED_D]; // 20 KB
    __shared__ float inv_l[CAPJ];
    __shared__ int   idx_l[CAPJ];
    __shared__ int   weq[16];

    const int c    = blockIdx.x;
    const int tid  = threadIdx.x;
    const int lane = tid & 63;
    const int wave = tid >> 6;

    // ---- phase 0: each thread owns 8 consecutive labels; scan ranks -------
    int4 la = *(const int4*)(labels + tid * 8);
    int4 lb = *(const int4*)(labels + tid * 8 + 4);
    int l[8] = {la.x, la.y, la.z, la.w, lb.x, lb.y, lb.z, lb.w};
    int meq = 0;
#pragma unroll
    for (int i = 0; i < 8; ++i) meq += (l[i] == c);
    int incl = meq;
#pragma unroll
    for (int o = 1; o < 64; o <<= 1) { int t = __shfl_up(incl, o); if (lane >= o) incl += t; }
    if (lane == 63) weq[wave] = incl;
    __syncthreads();
    int cnt = 0, wbase = 0;
#pragma unroll
    for (int w = 0; w < 16; ++w) { int q = weq[w]; cnt += q; if (w < wave) wbase += q; }
    if (cnt > CAPJ) cnt = CAPJ;                // unreachable memory-safety clamp
    int pos = wbase + incl - meq;
#pragma unroll
    for (int i = 0; i < 8; ++i)
        if (l[i] == c && pos < CAPJ) { idx_l[pos] = tid * 8 + i; ++pos; }
    __syncthreads();

    // ---- phase 1: similarities; wave-pair wp: token j, 5 protos; prefetch -
    {
        const int wp = wave >> 1, ph = wave & 1;
        float preg[5][8];
        const float* pb = protos + (size_t)(c * NUM_PROTO + ph * 5) * EMBED_D + lane * 8;
#pragma unroll
        for (int p = 0; p < 5; ++p) {
            float4 x = *(const float4*)(pb + p * EMBED_D);
            float4 y = *(const float4*)(pb + p * EMBED_D + 4);
            preg[p][0]=x.x; preg[p][1]=x.y; preg[p][2]=x.z; preg[p][3]=x.w;
            preg[p][4]=y.x; preg[p][5]=y.y; preg[p][6]=y.z; preg[p][7]=y.w;
        }
        int j = wp;
        float4 ta, tb;
        if (j < cnt) {
            const float* tr = tokens + (size_t)idx_l[j] * EMBED_D + lane * 8;
            ta = *(const float4*)tr;
            tb = *(const float4*)(tr + 4);
        }
        while (j < cnt) {
            int j2 = j + 8;
            float4 na, nb;
            if (j2 < cnt) {                      // prefetch next token row
                const float* tr = tokens + (size_t)idx_l[j2] * EMBED_D + lane * 8;
                na = *(const float4*)tr;
                nb = *(const float4*)(tr + 4);
            }
            float ssq = ta.x*ta.x + ta.y*ta.y + ta.z*ta.z + ta.w*ta.w
                      + tb.x*tb.x + tb.y*tb.y + tb.z*tb.z + tb.w*tb.w;
            ssq = wave_sum(ssq);
            float inv = 1.0f / sqrtf(ssq);
            if (ph == 0 && lane == 0) inv_l[j] = inv;
#pragma unroll
            for (int p = 0; p < 5; ++p) {
                float d = preg[p][0]*ta.x + preg[p][1]*ta.y + preg[p][2]*ta.z + preg[p][3]*ta.w
                        + preg[p][4]*tb.x + preg[p][5]*tb.y + preg[p][6]*tb.z + preg[p][7]*tb.w;
                d = wave_sum(d);
                if (lane == 0) S_sh[ph * 5 + p][j] = d * inv;
            }
            ta = na; tb = nb; j = j2;
        }
    }
    __syncthreads();

    // ---- phase 2: Sinkhorn on wave 0 only, in registers, zero barriers ----
    if (wave == 0 && cnt > 0) {
        const float log_a = -2.3025850f;       // log(0.1 + 1e-8)
        const float log_b = __logf(1.0f / (float)cnt + 1e-8f);
        const bool ok_a = lane < cnt, ok_b = lane + 64 < cnt;
        float Sa[NUM_PROTO], Sb[NUM_PROTO], u[NUM_PROTO];
#pragma unroll
        for (int p = 0; p < NUM_PROTO; ++p) {
            Sa[p] = ok_a ? S_sh[p][lane]      : -1e30f;
            Sb[p] = ok_b ? S_sh[p][lane + 64] : -1e30f;
        }
        float va = 0.0f, vb = 0.0f;
        for (int it = 0; it < ITERS; ++it) {
#pragma unroll
            for (int p = 0; p < NUM_PROTO; ++p) {
                float xa = (Sa[p] + va) * INV_EPS;
                float xb = (Sb[p] + vb) * INV_EPS;
                float M  = wave_max(fmaxf(xa, xb));
                float sm = wave_sum(__expf(xa - M) + __expf(xb - M));
                u[p] = EPSF * (log_a - (M + __logf(sm)));
            }
            if (it < ITERS - 1) {              // final v-update cancels in pi/colsum
                if (ok_a) {
                    float x[NUM_PROTO], m = -1e30f;
#pragma unroll
                    for (int p = 0; p < NUM_PROTO; ++p) { x[p] = (Sa[p] + u[p]) * INV_EPS; m = fmaxf(m, x[p]); }
                    float sm = 0.0f;
#pragma unroll
                    for (int p = 0; p < NUM_PROTO; ++p) sm += __expf(x[p] - m);
                    va = EPSF * (log_b - (m + __logf(sm)));
                }
                if (ok_b) {
                    float x[NUM_PROTO], m = -1e30f;
#pragma unroll
                    for (int p = 0; p < NUM_PROTO; ++p) { x[p] = (Sb[p] + u[p]) * INV_EPS; m = fmaxf(m, x[p]); }
                    float sm = 0.0f;
#pragma unroll
                    for (int p = 0; p < NUM_PROTO; ++p) sm += __expf(x[p] - m);
                    vb = EPSF * (log_b - (m + __logf(sm)));
                }
            }
        }
        // weights w[p][j] = softmax_p((S+u)/eps) * inv_norm -> S_sh
        if (ok_a) {
            float x[NUM_PROTO], m = -1e30f;
#pragma unroll
            for (int p = 0; p < NUM_PROTO; ++p) { x[p] = (Sa[p] + u[p]) * INV_EPS; m = fmaxf(m, x[p]); }
            float e[NUM_PROTO], cs = 0.0f;
#pragma unroll
            for (int p = 0; p < NUM_PROTO; ++p) { e[p] = __expf(x[p] - m); cs += e[p]; }
            float sc = inv_l[lane] / cs;
#pragma unroll
            for (int p = 0; p < NUM_PROTO; ++p) S_sh[p][lane] = e[p] * sc;
        }
        if (ok_b) {
            float x[NUM_PROTO], m = -1e30f;
#pragma unroll
            for (int p = 0; p < NUM_PROTO; ++p) { x[p] = (Sb[p] + u[p]) * INV_EPS; m = fmaxf(m, x[p]); }
            float e[NUM_PROTO], cs = 0.0f;
#pragma unroll
            for (int p = 0; p < NUM_PROTO; ++p) { e[p] = __expf(x[p] - m); cs += e[p]; }
            float sc = inv_l[lane + 64] / cs;
#pragma unroll
            for (int p = 0; p < NUM_PROTO; ++p) S_sh[p][lane + 64] = e[p] * sc;
        }
    }
    __syncthreads();

    // ---- phase 3: accumulate; wave (g,js): dims [g*128,+128), j += 4 ------
    const int g  = wave >> 2, js = wave & 3;
    const int d0 = g * 128 + lane * 2;
    float acc[NUM_PROTO][2];
#pragma unroll
    for (int p = 0; p < NUM_PROTO; ++p) { acc[p][0] = 0.0f; acc[p][1] = 0.0f; }
    for (int j = js; j < cnt; j += 4) {
        int n = idx_l[j];
        float2 t = *(const float2*)(tokens + (size_t)n * EMBED_D + d0);
#pragma unroll
        for (int p = 0; p < NUM_PROTO; ++p) {
            float w = S_sh[p][j];              // LDS broadcast
            acc[p][0] += w * t.x;
            acc[p][1] += w * t.y;
        }
    }
#pragma unroll
    for (int p = 0; p < NUM_PROTO; ++p)
        *(float2*)&red[wave][p][lane * 2] = make_float2(acc[p][0], acc[p][1]);
    __syncthreads();

    // ---- phase 4: reduce j-slices + momentum blend ------------------------
    for (int e4 = tid; e4 < NUM_PROTO * EMBED_D; e4 += 1024) {
        int p  = e4 >> 9;
        int d  = e4 & 511;
        int gg = d >> 7;
        int dd = d & 127;
        float s = red[gg * 4 + 0][p][dd] + red[gg * 4 + 1][p][dd]
                + red[gg * 4 + 2][p][dd] + red[gg * 4 + 3][p][dd];
        int row = c * NUM_PROTO + p;
        o_sh[p][d] = (1.0f - MOM) * protos[(size_t)row * EMBED_D + d] + MOM * s;
    }
    __syncthreads();

    // ---- phase 5: per-row L2 normalize + write ----------------------------
    if (wave < NUM_PROTO) {
        const float* orow = &o_sh[wave][0];
        float4 a = *(const float4*)(orow + lane * 8);
        float4 b = *(const float4*)(orow + lane * 8 + 4);
        float ss = a.x*a.x + a.y*a.y + a.z*a.z + a.w*a.w
                 + b.x*b.x + b.y*b.y + b.z*b.z + b.w*b.w;
        ss = wave_sum(ss);
        float inv = 1.0f / sqrtf(ss);
        int row = c * NUM_PROTO + wave;
        float* od = out + (size_t)row * EMBED_D + lane * 8;
        float4 w0 = make_float4(a.x*inv, a.y*inv, a.z*inv, a.w*inv);
        float4 w1 = make_float4(b.x*inv, b.y*inv, b.z*inv, b.w*inv);
        *(float4*)od       = w0;
        *(float4*)(od + 4) = w1;
    }
}

extern "C" void kernel_launch(void* const* d_in, const int* in_sizes, int n_in,
                              void* d_out, int out_size, void* d_ws, size_t ws_size,
                              hipStream_t stream) {
    const float* tokens = (const float*)d_in[0];
    const int*   labels = (const int*)d_in[1];
    const float* protos = (const float*)d_in[2];
    float* out = (float*)d_out;
    (void)d_ws; (void)ws_size; (void)in_sizes; (void)n_in; (void)out_size;

    k_all<<<NUM_CLASSES, 1024, 0, stream>>>(tokens, labels, protos, out);
}

// Round 11
// 34.699 us; speedup vs baseline: 1.7372x; 1.2204x over previous
//
#include <hip/hip_runtime.h>
#include <math.h>

#define NUM_CLASSES 200
#define NUM_PROTO   10
#define EMBED_D     512
#define NTOK        8192
#define INV_EPS     100.0f
#define EPSF        0.01f
#define MOM         0.02f
#define ITERS       5
#define CAPJ        128     // max class size (binomial mu=41 sigma=6.4; +13.6 sigma)

__device__ __forceinline__ float wave_sum(float v) {
#pragma unroll
    for (int o = 32; o; o >>= 1) v += __shfl_xor(v, o);
    return v;
}
__device__ __forceinline__ float wave_max(float v) {
#pragma unroll
    for (int o = 32; o; o >>= 1) v = fmaxf(v, __shfl_xor(v, o));
    return v;
}

// ---- single fused kernel: one block per class does EVERYTHING -------------
// phase 0: class-local count + stable rank of own tokens (scan, no atomics)
// phase 1: similarities S[10][cnt] into LDS (wave-pairs: 5 protos each,
//          1-deep token-row prefetch)
// phase 2: Sinkhorn wave-parallel (wave p: row LSE; thread j: col LSE);
//          final v-update dropped (cancels in pi/pi.sum(0))
// phase 3: accumulate new_proto (16 waves = 4 dimgroups x 4 j-slices),
//          4-deep batched token loads
// phase 4: reduce + momentum blend; phase 5: L2 normalize + write
__global__ __launch_bounds__(1024) void k_all(
        const float* __restrict__ tokens,
        const int*   __restrict__ labels,
        const float* __restrict__ protos,
        float*       __restrict__ out) {
    __shared__ float S_sh[NUM_PROTO][CAPJ];    // 5 KB
    __shared__ float red[16][NUM_PROTO][128];  // 80 KB
    __shared__ float o_sh[NUM_PROTO][EMBED_D]; // 20 KB
    __shared__ float v_sh[CAPJ];
    __shared__ float inv_l[CAPJ];
    __shared__ float u_sh[NUM_PROTO];
    __shared__ int   idx_l[CAPJ];
    __shared__ int   weq[16];

    const int c    = blockIdx.x;
    const int tid  = threadIdx.x;
    const int lane = tid & 63;
    const int wave = tid >> 6;

    // ---- phase 0: each thread owns 8 consecutive labels; scan ranks -------
    int4 la = *(const int4*)(labels + tid * 8);
    int4 lb = *(const int4*)(labels + tid * 8 + 4);
    int l[8] = {la.x, la.y, la.z, la.w, lb.x, lb.y, lb.z, lb.w};
    int meq = 0;
#pragma unroll
    for (int i = 0; i < 8; ++i) meq += (l[i] == c);
    int incl = meq;
#pragma unroll
    for (int o = 1; o < 64; o <<= 1) { int t = __shfl_up(incl, o); if (lane >= o) incl += t; }
    if (lane == 63) weq[wave] = incl;
    if (tid < CAPJ) v_sh[tid] = 0.0f;
    __syncthreads();
    int cnt = 0, wbase = 0;
#pragma unroll
    for (int w = 0; w < 16; ++w) { int q = weq[w]; cnt += q; if (w < wave) wbase += q; }
    if (cnt > CAPJ) cnt = CAPJ;                // unreachable memory-safety clamp
    int pos = wbase + incl - meq;
#pragma unroll
    for (int i = 0; i < 8; ++i)
        if (l[i] == c && pos < CAPJ) { idx_l[pos] = tid * 8 + i; ++pos; }
    __syncthreads();

    // ---- phase 1: similarities; wave-pair wp: token j, 5 protos; prefetch -
    {
        const int wp = wave >> 1, ph = wave & 1;
        float preg[5][8];
        const float* pb = protos + (size_t)(c * NUM_PROTO + ph * 5) * EMBED_D + lane * 8;
#pragma unroll
        for (int p = 0; p < 5; ++p) {
            float4 x = *(const float4*)(pb + p * EMBED_D);
            float4 y = *(const float4*)(pb + p * EMBED_D + 4);
            preg[p][0]=x.x; preg[p][1]=x.y; preg[p][2]=x.z; preg[p][3]=x.w;
            preg[p][4]=y.x; preg[p][5]=y.y; preg[p][6]=y.z; preg[p][7]=y.w;
        }
        int j = wp;
        float4 ta, tb;
        if (j < cnt) {
            const float* tr = tokens + (size_t)idx_l[j] * EMBED_D + lane * 8;
            ta = *(const float4*)tr;
            tb = *(const float4*)(tr + 4);
        }
        while (j < cnt) {
            int j2 = j + 8;
            float4 na, nb;
            if (j2 < cnt) {                      // prefetch next token row
                const float* tr = tokens + (size_t)idx_l[j2] * EMBED_D + lane * 8;
                na = *(const float4*)tr;
                nb = *(const float4*)(tr + 4);
            }
            float ssq = ta.x*ta.x + ta.y*ta.y + ta.z*ta.z + ta.w*ta.w
                      + tb.x*tb.x + tb.y*tb.y + tb.z*tb.z + tb.w*tb.w;
            ssq = wave_sum(ssq);
            float inv = 1.0f / sqrtf(ssq);
            if (ph == 0 && lane == 0) inv_l[j] = inv;
#pragma unroll
            for (int p = 0; p < 5; ++p) {
                float d = preg[p][0]*ta.x + preg[p][1]*ta.y + preg[p][2]*ta.z + preg[p][3]*ta.w
                        + preg[p][4]*tb.x + preg[p][5]*tb.y + preg[p][6]*tb.z + preg[p][7]*tb.w;
                d = wave_sum(d);
                if (lane == 0) S_sh[ph * 5 + p][j] = d * inv;
            }
            ta = na; tb = nb; j = j2;
        }
    }
    __syncthreads();

    // ---- phase 2: Sinkhorn (wave p: row LSE; thread j: col LSE) -----------
    const float log_a = -2.3025850f;           // log(0.1 + 1e-8)
    const float log_b = __logf(1.0f / (float)(cnt > 0 ? cnt : 1) + 1e-8f);
    for (int it = 0; it < ITERS; ++it) {
        if (wave < NUM_PROTO) {
            int j1 = lane + 64;
            float x0 = (lane < cnt) ? (S_sh[wave][lane] + v_sh[lane]) * INV_EPS : -1e30f;
            float x1 = (j1  < cnt) ? (S_sh[wave][j1]  + v_sh[j1])  * INV_EPS : -1e30f;
            float M  = wave_max(fmaxf(x0, x1));
            float sm = wave_sum(__expf(x0 - M) + __expf(x1 - M));
            if (lane == 0) u_sh[wave] = EPSF * (log_a - (M + __logf(sm)));
        }
        __syncthreads();
        if (it < ITERS - 1) {                  // final v-update cancels in pi/colsum
            if (tid < cnt) {
                float x[NUM_PROTO], m = -1e30f;
#pragma unroll
                for (int p = 0; p < NUM_PROTO; ++p) {
                    x[p] = (S_sh[p][tid] + u_sh[p]) * INV_EPS;
                    m = fmaxf(m, x[p]);
                }
                float sm = 0.0f;
#pragma unroll
                for (int p = 0; p < NUM_PROTO; ++p) sm += __expf(x[p] - m);
                v_sh[tid] = EPSF * (log_b - (m + __logf(sm)));
            }
            __syncthreads();
        }
    }
    // weights w[p][j] = softmax_p((S+u)/eps) * inv_norm  (v cancels exactly)
    if (tid < cnt) {
        float x[NUM_PROTO], m = -1e30f;
#pragma unroll
        for (int p = 0; p < NUM_PROTO; ++p) {
            x[p] = (S_sh[p][tid] + u_sh[p]) * INV_EPS;
            m = fmaxf(m, x[p]);
        }
        float e[NUM_PROTO], cs = 0.0f;
#pragma unroll
        for (int p = 0; p < NUM_PROTO; ++p) { e[p] = __expf(x[p] - m); cs += e[p]; }
        float sc = inv_l[tid] / cs;
#pragma unroll
        for (int p = 0; p < NUM_PROTO; ++p) S_sh[p][tid] = e[p] * sc;
    }
    __syncthreads();

    // ---- phase 3: accumulate; wave (g,js): dims [g*128,+128), 4-deep ------
    const int g  = wave >> 2, js = wave & 3;
    const int d0 = g * 128 + lane * 2;
    float acc[NUM_PROTO][2];
#pragma unroll
    for (int p = 0; p < NUM_PROTO; ++p) { acc[p][0] = 0.0f; acc[p][1] = 0.0f; }
    for (int j0 = js; j0 < cnt; j0 += 16) {          // 4 tokens in flight
        float2 T[4];
#pragma unroll
        for (int k = 0; k < 4; ++k) {
            int j = j0 + 4 * k;
            if (j < cnt) T[k] = *(const float2*)(tokens + (size_t)idx_l[j] * EMBED_D + d0);
        }
#pragma unroll
        for (int k = 0; k < 4; ++k) {
            int j = j0 + 4 * k;
            if (j < cnt) {
#pragma unroll
                for (int p = 0; p < NUM_PROTO; ++p) {
                    float w = S_sh[p][j];      // LDS broadcast
                    acc[p][0] += w * T[k].x;
                    acc[p][1] += w * T[k].y;
                }
            }
        }
    }
#pragma unroll
    for (int p = 0; p < NUM_PROTO; ++p)
        *(float2*)&red[wave][p][lane * 2] = make_float2(acc[p][0], acc[p][1]);
    __syncthreads();

    // ---- phase 4: reduce j-slices + momentum blend ------------------------
    for (int e4 = tid; e4 < NUM_PROTO * EMBED_D; e4 += 1024) {
        int p  = e4 >> 9;
        int d  = e4 & 511;
        int gg = d >> 7;
        int dd = d & 127;
        float s = red[gg * 4 + 0][p][dd] + red[gg * 4 + 1][p][dd]
                + red[gg * 4 + 2][p][dd] + red[gg * 4 + 3][p][dd];
        int row = c * NUM_PROTO + p;
        o_sh[p][d] = (1.0f - MOM) * protos[(size_t)row * EMBED_D + d] + MOM * s;
    }
    __syncthreads();

    // ---- phase 5: per-row L2 normalize + write ----------------------------
    if (wave < NUM_PROTO) {
        const float* orow = &o_sh[wave][0];
        float4 a = *(const float4*)(orow + lane * 8);
        float4 b = *(const float4*)(orow + lane * 8 + 4);
        float ss = a.x*a.x + a.y*a.y + a.z*a.z + a.w*a.w
                 + b.x*b.x + b.y*b.y + b.z*b.z + b.w*b.w;
        ss = wave_sum(ss);
        float inv = 1.0f / sqrtf(ss);
        int row = c * NUM_PROTO + wave;
        float* od = out + (size_t)row * EMBED_D + lane * 8;
        float4 w0 = make_float4(a.x*inv, a.y*inv, a.z*inv, a.w*inv);
        float4 w1 = make_float4(b.x*inv, b.y*inv, b.z*inv, b.w*inv);
        *(float4*)od       = w0;
        *(float4*)(od + 4) = w1;
    }
}

extern "C" void kernel_launch(void* const* d_in, const int* in_sizes, int n_in,
                              void* d_out, int out_size, void* d_ws, size_t ws_size,
                              hipStream_t stream) {
    const float* tokens = (const float*)d_in[0];
    const int*   labels = (const int*)d_in[1];
    const float* protos = (const float*)d_in[2];
    float* out = (float*)d_out;
    (void)d_ws; (void)ws_size; (void)in_sizes; (void)n_in; (void)out_size;

    k_all<<<NUM_CLASSES, 1024, 0, stream>>>(tokens, labels, protos, out);
}

// Round 12
// 33.522 us; speedup vs baseline: 1.7982x; 1.0351x over previous
//
#include <hip/hip_runtime.h>
#include <math.h>

#define NUM_CLASSES 200
#define NUM_PROTO   10
#define EMBED_D     512
#define NTOK        8192
#define INV_EPS     100.0f
#define EPSF        0.01f
#define MOM         0.02f
#define ITERS       5
#define CAPJ        128     // max class size (binomial mu=41 sigma=6.4; +13.6 sigma)

__device__ __forceinline__ float wave_sum(float v) {
#pragma unroll
    for (int o = 32; o; o >>= 1) v += __shfl_xor(v, o);
    return v;
}
__device__ __forceinline__ float wave_max(float v) {
#pragma unroll
    for (int o = 32; o; o >>= 1) v = fmaxf(v, __shfl_xor(v, o));
    return v;
}

// ---- single fused kernel: one block per class does EVERYTHING -------------
// phase 0: class-local count + stable rank of own tokens (scan, no atomics)
// phase 1: similarities S[10][cnt] into LDS; wave-pair handles 2 tokens per
//          iteration, 12 reductions (2 ssq + 2x5 sims) in ONE interleaved
//          6-stage butterfly (12-way ILP per stage)
// phase 2: Sinkhorn wave-parallel (wave p: row LSE; thread j: col LSE);
//          final v-update dropped (cancels in pi/pi.sum(0))
// phase 3: accumulate new_proto (16 waves = 4 dimgroups x 4 j-slices)
// phase 4: reduce + momentum blend; phase 5: L2 normalize + write
__global__ __launch_bounds__(1024) void k_all(
        const float* __restrict__ tokens,
        const int*   __restrict__ labels,
        const float* __restrict__ protos,
        float*       __restrict__ out) {
    __shared__ float S_sh[NUM_PROTO][CAPJ];    // 5 KB
    __shared__ float red[16][NUM_PROTO][128];  // 80 KB
    __shared__ float o_sh[NUM_PROTO][EMBED_D]; // 20 KB
    __shared__ float v_sh[CAPJ];
    __shared__ float inv_l[CAPJ];
    __shared__ float u_sh[NUM_PROTO];
    __shared__ int   idx_l[CAPJ];
    __shared__ int   weq[16];

    const int c    = blockIdx.x;
    const int tid  = threadIdx.x;
    const int lane = tid & 63;
    const int wave = tid >> 6;

    // ---- phase 0: each thread owns 8 consecutive labels; scan ranks -------
    int4 la = *(const int4*)(labels + tid * 8);
    int4 lb = *(const int4*)(labels + tid * 8 + 4);
    int l[8] = {la.x, la.y, la.z, la.w, lb.x, lb.y, lb.z, lb.w};
    int meq = 0;
#pragma unroll
    for (int i = 0; i < 8; ++i) meq += (l[i] == c);
    int incl = meq;
#pragma unroll
    for (int o = 1; o < 64; o <<= 1) { int t = __shfl_up(incl, o); if (lane >= o) incl += t; }
    if (lane == 63) weq[wave] = incl;
    if (tid < CAPJ) v_sh[tid] = 0.0f;
    __syncthreads();
    int cnt = 0, wbase = 0;
#pragma unroll
    for (int w = 0; w < 16; ++w) { int q = weq[w]; cnt += q; if (w < wave) wbase += q; }
    if (cnt > CAPJ) cnt = CAPJ;                // unreachable memory-safety clamp
    int pos = wbase + incl - meq;
#pragma unroll
    for (int i = 0; i < 8; ++i)
        if (l[i] == c && pos < CAPJ) { idx_l[pos] = tid * 8 + i; ++pos; }
    __syncthreads();

    // ---- phase 1: wave-pair wp: tokens {j, j+8}, 5 protos (ph half) -------
    {
        const int wp = wave >> 1, ph = wave & 1;
        float preg[5][8];
        const float* pb = protos + (size_t)(c * NUM_PROTO + ph * 5) * EMBED_D + lane * 8;
#pragma unroll
        for (int p = 0; p < 5; ++p) {
            float4 x = *(const float4*)(pb + p * EMBED_D);
            float4 y = *(const float4*)(pb + p * EMBED_D + 4);
            preg[p][0]=x.x; preg[p][1]=x.y; preg[p][2]=x.z; preg[p][3]=x.w;
            preg[p][4]=y.x; preg[p][5]=y.y; preg[p][6]=y.z; preg[p][7]=y.w;
        }
        for (int j0 = wp; j0 < cnt; j0 += 16) {
            const int jB = j0 + 8;
            const bool hasB = jB < cnt;
            // issue both token-row loads together (2 rows in flight)
            const float* trA = tokens + (size_t)idx_l[j0] * EMBED_D + lane * 8;
            float4 a0 = *(const float4*)trA;
            float4 a1 = *(const float4*)(trA + 4);
            float4 b0 = make_float4(0.f,0.f,0.f,0.f), b1 = b0;
            if (hasB) {
                const float* trB = tokens + (size_t)idx_l[jB] * EMBED_D + lane * 8;
                b0 = *(const float4*)trB;
                b1 = *(const float4*)(trB + 4);
            }
            // 12 independent partials: [0]=ssqA [1]=ssqB [2..6]=dotsA [7..11]=dotsB
            float r[12];
            r[0] = a0.x*a0.x + a0.y*a0.y + a0.z*a0.z + a0.w*a0.w
                 + a1.x*a1.x + a1.y*a1.y + a1.z*a1.z + a1.w*a1.w;
            r[1] = b0.x*b0.x + b0.y*b0.y + b0.z*b0.z + b0.w*b0.w
                 + b1.x*b1.x + b1.y*b1.y + b1.z*b1.z + b1.w*b1.w + 1e-30f;
#pragma unroll
            for (int p = 0; p < 5; ++p) {
                r[2 + p] = preg[p][0]*a0.x + preg[p][1]*a0.y + preg[p][2]*a0.z + preg[p][3]*a0.w
                         + preg[p][4]*a1.x + preg[p][5]*a1.y + preg[p][6]*a1.z + preg[p][7]*a1.w;
                r[7 + p] = preg[p][0]*b0.x + preg[p][1]*b0.y + preg[p][2]*b0.z + preg[p][3]*b0.w
                         + preg[p][4]*b1.x + preg[p][5]*b1.y + preg[p][6]*b1.z + preg[p][7]*b1.w;
            }
            // one interleaved butterfly: 6 stages x 12 independent chains
#pragma unroll
            for (int o = 32; o; o >>= 1) {
#pragma unroll
                for (int i = 0; i < 12; ++i) r[i] += __shfl_xor(r[i], o);
            }
            float invA = 1.0f / sqrtf(r[0]);
            float invB = 1.0f / sqrtf(r[1]);
            if (lane == 0) {
                if (ph == 0) inv_l[j0] = invA;
#pragma unroll
                for (int p = 0; p < 5; ++p) S_sh[ph * 5 + p][j0] = r[2 + p] * invA;
                if (hasB) {
                    if (ph == 0) inv_l[jB] = invB;
#pragma unroll
                    for (int p = 0; p < 5; ++p) S_sh[ph * 5 + p][jB] = r[7 + p] * invB;
                }
            }
        }
    }
    __syncthreads();

    // ---- phase 2: Sinkhorn (wave p: row LSE; thread j: col LSE) -----------
    const float log_a = -2.3025850f;           // log(0.1 + 1e-8)
    const float log_b = __logf(1.0f / (float)(cnt > 0 ? cnt : 1) + 1e-8f);
    for (int it = 0; it < ITERS; ++it) {
        if (wave < NUM_PROTO) {
            int j1 = lane + 64;
            float x0 = (lane < cnt) ? (S_sh[wave][lane] + v_sh[lane]) * INV_EPS : -1e30f;
            float x1 = (j1  < cnt) ? (S_sh[wave][j1]  + v_sh[j1])  * INV_EPS : -1e30f;
            float M  = wave_max(fmaxf(x0, x1));
            float sm = wave_sum(__expf(x0 - M) + __expf(x1 - M));
            if (lane == 0) u_sh[wave] = EPSF * (log_a - (M + __logf(sm)));
        }
        __syncthreads();
        if (it < ITERS - 1) {                  // final v-update cancels in pi/colsum
            if (tid < cnt) {
                float x[NUM_PROTO], m = -1e30f;
#pragma unroll
                for (int p = 0; p < NUM_PROTO; ++p) {
                    x[p] = (S_sh[p][tid] + u_sh[p]) * INV_EPS;
                    m = fmaxf(m, x[p]);
                }
                float sm = 0.0f;
#pragma unroll
                for (int p = 0; p < NUM_PROTO; ++p) sm += __expf(x[p] - m);
                v_sh[tid] = EPSF * (log_b - (m + __logf(sm)));
            }
            __syncthreads();
        }
    }
    // weights w[p][j] = softmax_p((S+u)/eps) * inv_norm  (v cancels exactly)
    if (tid < cnt) {
        float x[NUM_PROTO], m = -1e30f;
#pragma unroll
        for (int p = 0; p < NUM_PROTO; ++p) {
            x[p] = (S_sh[p][tid] + u_sh[p]) * INV_EPS;
            m = fmaxf(m, x[p]);
        }
        float e[NUM_PROTO], cs = 0.0f;
#pragma unroll
        for (int p = 0; p < NUM_PROTO; ++p) { e[p] = __expf(x[p] - m); cs += e[p]; }
        float sc = inv_l[tid] / cs;
#pragma unroll
        for (int p = 0; p < NUM_PROTO; ++p) S_sh[p][tid] = e[p] * sc;
    }
    __syncthreads();

    // ---- phase 3: accumulate; wave (g,js): dims [g*128,+128), j += 4 ------
    const int g  = wave >> 2, js = wave & 3;
    const int d0 = g * 128 + lane * 2;
    float acc[NUM_PROTO][2];
#pragma unroll
    for (int p = 0; p < NUM_PROTO; ++p) { acc[p][0] = 0.0f; acc[p][1] = 0.0f; }
    for (int j = js; j < cnt; j += 4) {
        int n = idx_l[j];
        float2 t = *(const float2*)(tokens + (size_t)n * EMBED_D + d0);
#pragma unroll
        for (int p = 0; p < NUM_PROTO; ++p) {
            float w = S_sh[p][j];              // LDS broadcast
            acc[p][0] += w * t.x;
            acc[p][1] += w * t.y;
        }
    }
#pragma unroll
    for (int p = 0; p < NUM_PROTO; ++p)
        *(float2*)&red[wave][p][lane * 2] = make_float2(acc[p][0], acc[p][1]);
    __syncthreads();

    // ---- phase 4: reduce j-slices + momentum blend ------------------------
    for (int e4 = tid; e4 < NUM_PROTO * EMBED_D; e4 += 1024) {
        int p  = e4 >> 9;
        int d  = e4 & 511;
        int gg = d >> 7;
        int dd = d & 127;
        float s = red[gg * 4 + 0][p][dd] + red[gg * 4 + 1][p][dd]
                + red[gg * 4 + 2][p][dd] + red[gg * 4 + 3][p][dd];
        int row = c * NUM_PROTO + p;
        o_sh[p][d] = (1.0f - MOM) * protos[(size_t)row * EMBED_D + d] + MOM * s;
    }
    __syncthreads();

    // ---- phase 5: per-row L2 normalize + write ----------------------------
    if (wave < NUM_PROTO) {
        const float* orow = &o_sh[wave][0];
        float4 a = *(const float4*)(orow + lane * 8);
        float4 b = *(const float4*)(orow + lane * 8 + 4);
        float ss = a.x*a.x + a.y*a.y + a.z*a.z + a.w*a.w
                 + b.x*b.x + b.y*b.y + b.z*b.z + b.w*b.w;
        ss = wave_sum(ss);
        float inv = 1.0f / sqrtf(ss);
        int row = c * NUM_PROTO + wave;
        float* od = out + (size_t)row * EMBED_D + lane * 8;
        float4 w0 = make_float4(a.x*inv, a.y*inv, a.z*inv, a.w*inv);
        float4 w1 = make_float4(b.x*inv, b.y*inv, b.z*inv, b.w*inv);
        *(float4*)od       = w0;
        *(float4*)(od + 4) = w1;
    }
}

extern "C" void kernel_launch(void* const* d_in, const int* in_sizes, int n_in,
                              void* d_out, int out_size, void* d_ws, size_t ws_size,
                              hipStream_t stream) {
    const float* tokens = (const float*)d_in[0];
    const int*   labels = (const int*)d_in[1];
    const float* protos = (const float*)d_in[2];
    float* out = (float*)d_out;
    (void)d_ws; (void)ws_size; (void)in_sizes; (void)n_in; (void)out_size;

    k_all<<<NUM_CLASSES, 1024, 0, stream>>>(tokens, labels, protos, out);
}